// Round 2
// baseline (551.636 us; speedup 1.0000x reference)
//
#include <hip/hip_runtime.h>
#include <math.h>

#define BB 64
#define NN 32768
#define CC 2
#define DD1 32
#define DD2 64

typedef float v4f __attribute__((ext_vector_type(4)));
typedef float v2f __attribute__((ext_vector_type(2)));

// ws layout (floats): Cb[BB][DD2] at offset 0 ; M[2][DD2] at offset BB*DD2.

__global__ __launch_bounds__(1024) void prep_kernel(
    const float* __restrict__ x,   // [B,N,2]
    const float* __restrict__ W1,  // [2,32]
    const float* __restrict__ b1,  // [32]
    const float* __restrict__ G1,  // [2,32]
    const float* __restrict__ W2,  // [32,64]
    const float* __restrict__ b2,  // [64]
    float* __restrict__ ws)
{
    const int b   = blockIdx.x;
    const int tid = threadIdx.x;

    // ---- phase 1: per-batch max over N points, channels 0 and 1 ----
    const float4* xb = (const float4*)(x + (size_t)b * NN * CC); // 16384 float4 = 2 pts each
    float m0 = -INFINITY, m1 = -INFINITY;
    for (int i = tid; i < (NN * CC) / 4; i += 1024) {
        float4 v = xb[i];
        m0 = fmaxf(m0, fmaxf(v.x, v.z));
        m1 = fmaxf(m1, fmaxf(v.y, v.w));
    }
    // wave (64-lane) butterfly
    for (int off = 32; off >= 1; off >>= 1) {
        m0 = fmaxf(m0, __shfl_down(m0, off));
        m1 = fmaxf(m1, __shfl_down(m1, off));
    }
    __shared__ float s0[16], s1[16];
    __shared__ float beta0_s, beta1_s;
    const int wave = tid >> 6, lane = tid & 63;
    if (lane == 0) { s0[wave] = m0; s1[wave] = m1; }
    __syncthreads();
    if (tid == 0) {
        float a = s0[0], c = s1[0];
        for (int w = 1; w < 16; ++w) { a = fmaxf(a, s0[w]); c = fmaxf(c, s1[w]); }
        beta0_s = a; beta1_s = c;
    }
    __syncthreads();

    // ---- phase 2: Cb[b][d] = sum_k (b1[k] - beta@G1)[k] * W2[k][d] + b2[d] ----
    if (tid < DD2) {
        const int d = tid;
        const float B0 = beta0_s, B1 = beta1_s;
        float acc = b2[d];
        for (int k = 0; k < DD1; ++k) {
            float t = b1[k] - B0 * G1[k] - B1 * G1[DD1 + k];
            acc = fmaf(t, W2[k * DD2 + d], acc);
        }
        ws[b * DD2 + d] = acc;
    }
    // ---- phase 3 (block 0 only): M[r][d] = sum_k W1[r][k] * W2[k][d] ----
    if (b == 0 && tid >= 64 && tid < 64 + 2 * DD2) {
        const int idx = tid - 64;
        const int r = idx >> 6, d = idx & 63;
        float acc = 0.f;
        for (int k = 0; k < DD1; ++k)
            acc = fmaf(W1[r * DD1 + k], W2[k * DD2 + d], acc);
        ws[BB * DD2 + idx] = acc;
    }
}

// Persistent-resident main kernel:
//   2048 blocks x 256 threads = 8192 waves = 32 waves/CU on 256 CUs -> every
//   block resident, no block churn. Each block owns 16 tiles of 64 points
//   (256 KiB of stores), looping j = 0..15.
// Mapping inside a tile (provably coalesced):
//   16 lanes per point, lane's d4 = tid&15 picks one float4 of the 64-dim
//   output; per-wave store address = pointBase*16 + it*256 + tid -> contiguous
//   1 KiB per wave, 4 KiB per block-iteration.
// Stores are nontemporal (nt): 512 MiB streaming output must not thrash L2.
#define BLOCKS_PER_BATCH 32                      // 2048 blocks total
#define TILES_PER_BATCH  (NN / 64)               // 512
#define TILES_PER_BLOCK  (TILES_PER_BATCH / BLOCKS_PER_BATCH)  // 16

__global__ __launch_bounds__(256) void main_kernel(
    const float* __restrict__ x,   // [B,N,2]
    const float* __restrict__ ws,  // Cb + M
    float* __restrict__ out)       // [B,N,64]
{
    const int tid = threadIdx.x;
    const int d4  = tid & 15;
    const int g   = tid >> 4;                    // 0..15: point within iter group
    const int b   = blockIdx.x >> 5;             // batch (32 blocks per batch)
    const int blk = blockIdx.x & 31;             // block index within batch

    const v4f cb  = ((const v4f*)(ws + b * DD2))[d4];
    const v4f mm0 = ((const v4f*)(ws + BB * DD2))[d4];
    const v4f mm1 = ((const v4f*)(ws + BB * DD2 + DD2))[d4];

    const long long batchBase = (long long)b * NN;

    #pragma unroll 1
    for (int j = 0; j < TILES_PER_BLOCK; ++j) {
        const long long pointBase =
            batchBase + (long long)(blk + j * BLOCKS_PER_BATCH) * 64;

        // Issue all 4 point-loads first (independent, broadcast across 16 lanes),
        // then the dependent FMA+store chain: keeps 4 loads + 4 stores in flight.
        v2f xv0 = ((const v2f*)x)[pointBase +  0 + g];
        v2f xv1 = ((const v2f*)x)[pointBase + 16 + g];
        v2f xv2 = ((const v2f*)x)[pointBase + 32 + g];
        v2f xv3 = ((const v2f*)x)[pointBase + 48 + g];

        v4f* outBase = ((v4f*)out) + pointBase * 16 + (long long)g * 16 + d4;

        v4f o0;
        o0.x = fmaf(xv0.x, mm0.x, fmaf(xv0.y, mm1.x, cb.x));
        o0.y = fmaf(xv0.x, mm0.y, fmaf(xv0.y, mm1.y, cb.y));
        o0.z = fmaf(xv0.x, mm0.z, fmaf(xv0.y, mm1.z, cb.z));
        o0.w = fmaf(xv0.x, mm0.w, fmaf(xv0.y, mm1.w, cb.w));
        __builtin_nontemporal_store(o0, outBase + 0 * 256);

        v4f o1;
        o1.x = fmaf(xv1.x, mm0.x, fmaf(xv1.y, mm1.x, cb.x));
        o1.y = fmaf(xv1.x, mm0.y, fmaf(xv1.y, mm1.y, cb.y));
        o1.z = fmaf(xv1.x, mm0.z, fmaf(xv1.y, mm1.z, cb.z));
        o1.w = fmaf(xv1.x, mm0.w, fmaf(xv1.y, mm1.w, cb.w));
        __builtin_nontemporal_store(o1, outBase + 1 * 256);

        v4f o2;
        o2.x = fmaf(xv2.x, mm0.x, fmaf(xv2.y, mm1.x, cb.x));
        o2.y = fmaf(xv2.x, mm0.y, fmaf(xv2.y, mm1.y, cb.y));
        o2.z = fmaf(xv2.x, mm0.z, fmaf(xv2.y, mm1.z, cb.z));
        o2.w = fmaf(xv2.x, mm0.w, fmaf(xv2.y, mm1.w, cb.w));
        __builtin_nontemporal_store(o2, outBase + 2 * 256);

        v4f o3;
        o3.x = fmaf(xv3.x, mm0.x, fmaf(xv3.y, mm1.x, cb.x));
        o3.y = fmaf(xv3.x, mm0.y, fmaf(xv3.y, mm1.y, cb.y));
        o3.z = fmaf(xv3.x, mm0.z, fmaf(xv3.y, mm1.z, cb.z));
        o3.w = fmaf(xv3.x, mm0.w, fmaf(xv3.y, mm1.w, cb.w));
        __builtin_nontemporal_store(o3, outBase + 3 * 256);
    }
}

extern "C" void kernel_launch(void* const* d_in, const int* in_sizes, int n_in,
                              void* d_out, int out_size, void* d_ws, size_t ws_size,
                              hipStream_t stream) {
    const float* x  = (const float*)d_in[0];
    const float* W1 = (const float*)d_in[1];
    const float* b1 = (const float*)d_in[2];
    const float* G1 = (const float*)d_in[3];
    const float* W2 = (const float*)d_in[4];
    const float* b2 = (const float*)d_in[5];
    float* out = (float*)d_out;
    float* ws  = (float*)d_ws;

    prep_kernel<<<BB, 1024, 0, stream>>>(x, W1, b1, G1, W2, b2, ws);
    main_kernel<<<BB * BLOCKS_PER_BATCH, 256, 0, stream>>>(x, ws, out);
}